// Round 5
// baseline (46076.437 us; speedup 1.0000x reference)
//
#include <hip/hip_runtime.h>
#include <hip/hip_cooperative_groups.h>
#include <stdint.h>

namespace cg = cooperative_groups;

typedef unsigned short u16;
typedef __bf16 bf16x8 __attribute__((ext_vector_type(8)));
typedef u16    u16x8  __attribute__((ext_vector_type(8)));
typedef float  f32x4  __attribute__((ext_vector_type(4)));

#define TSTEPS 100
#define BATCH  256
#define INDIM  700
#define HID    2048
#define ODIM   20

#define KS_IN  22            // ceil(700/32)
#define KS_HID 64            // 2048/32
#define JT_HID 128           // 2048/16
#define PS_IN  ((size_t)JT_HID*KS_IN*512)    // elems per plane (L0)
#define PS_HID ((size_t)JT_HID*KS_HID*512)   // elems per plane (hidden)
#define PS_OUT ((size_t)2*KS_HID*512)        // elems per plane (L4, N padded to 32)

__device__ __forceinline__ bf16x8 ldb8(const u16* p) {
  return *reinterpret_cast<const bf16x8*>(p);
}

__device__ __forceinline__ f32x4 mf(bf16x8 a, bf16x8 b, f32x4 c) {
  return __builtin_amdgcn_mfma_f32_16x16x32_bf16(a, b, c, 0, 0, 0);
}

// ------------------------------ init ------------------------------
__global__ void k_zero(float4* __restrict__ p, int n4) {
  int i = blockIdx.x * 256 + threadIdx.x;
  int s = gridDim.x * 256;
  float4 z; z.x = 0.f; z.y = 0.f; z.z = 0.f; z.w = 0.f;
  for (; i < n4; i += s) p[i] = z;
}

// -------------------- weight split into fragment layout --------------------
// chunk c = (jt*KS + ks)*64 + lane ; elem e of chunk holds
//   plane_p( W[jt*16 + (lane&15)][ks*32 + (lane>>4)*8 + e] )
__global__ void k_split(const float* __restrict__ W, u16* __restrict__ outp,
                        int N, int K, int KS, int nchunks, int planes, size_t ps) {
  int c = blockIdx.x * 256 + threadIdx.x;
  if (c >= nchunks) return;
  int lane = c & 63;
  int t  = c >> 6;
  int ks = t % KS;
  int jt = t / KS;
  int j  = jt * 16 + (lane & 15);
  int k0 = ks * 32 + ((lane >> 4) << 3);
  float x[8];
  if (j < N) {
    const float* wr = W + (size_t)j * K;
    if (k0 + 7 < K) {
      float4 v0 = *reinterpret_cast<const float4*>(wr + k0);
      float4 v1 = *reinterpret_cast<const float4*>(wr + k0 + 4);
      x[0]=v0.x; x[1]=v0.y; x[2]=v0.z; x[3]=v0.w;
      x[4]=v1.x; x[5]=v1.y; x[6]=v1.z; x[7]=v1.w;
    } else {
      #pragma unroll
      for (int e = 0; e < 8; e++) x[e] = (k0 + e < K) ? wr[k0 + e] : 0.0f;
    }
  } else {
    #pragma unroll
    for (int e = 0; e < 8; e++) x[e] = 0.0f;
  }
  u16x8 vh, vm, vl;
  #pragma unroll
  for (int e = 0; e < 8; e++) {
    float w   = x[e];
    __bf16 bh = (__bf16)w;            // RNE
    float r1  = w - (float)bh;        // exact
    __bf16 bm = (__bf16)r1;
    __bf16 bl = (__bf16)(r1 - (float)bm);
    vh[e] = __builtin_bit_cast(unsigned short, bh);
    vm[e] = __builtin_bit_cast(unsigned short, bm);
    vl[e] = __builtin_bit_cast(unsigned short, bl);
  }
  size_t base = (size_t)c * 8;
  *reinterpret_cast<u16x8*>(outp + base) = vh;
  if (planes > 1) *reinterpret_cast<u16x8*>(outp + ps     + base) = vm;
  if (planes > 2) *reinterpret_cast<u16x8*>(outp + 2 * ps + base) = vl;
}

// ------------------------------ LIF ------------------------------
__device__ __forceinline__ void lif_store(float cur, float* __restrict__ mem,
                                          size_t idx, u16* __restrict__ spk) {
  float mo = mem[idx];
  float mn = 0.9f * mo + cur - ((mo > 1.0f) ? 1.0f : 0.0f);
  mem[idx] = mn;
  spk[idx] = (mn - 1.0f > 0.0f) ? (u16)0x3F80 : (u16)0;   // bf16 1.0 / 0.0 (exact)
}

// --------------------------- hidden-layer phase ---------------------------
// 256 blocks = 4 mt x 64 nt (XCD = nt%8). 8 waves: (jf, mfh, kh); kh splits K.
// 3-buffer fully-unrolled pipeline: pair i lives in buffer i%3; prefetch
// distance = 2 pairs (~930 SIMD cyc with 2 waves/SIMD) — covers L3/HBM.
template<int P>
__device__ __forceinline__ void phase_hid(
    int bid, int tid, const u16* __restrict__ A, const u16* __restrict__ Wf,
    const float* __restrict__ bias, float* __restrict__ mem,
    u16* __restrict__ spk_out, float (&red)[8][512]) {
  int mt = bid >> 6, nt = bid & 63;
  int wid = tid >> 6, lane = tid & 63;
  int r15 = lane & 15, g = lane >> 4;
  int jf = wid & 1, mfh = (wid >> 1) & 1, kh = wid >> 2;
  const int ksb = kh * (KS_HID / 2);
  constexpr int NP = KS_HID / 4;              // 16 pairs per half

  const u16* wb = Wf + ((size_t)(nt * 2 + jf) * KS_HID) * 512 + (size_t)lane * 8;
  const u16* a0 = A + (size_t)(mt * 64 + mfh * 32 + r15) * HID + g * 8;
  const u16* a1 = a0 + 16 * HID;

  f32x4 c0a{}, c1a{}, c0b{}, c1b{};
  bf16x8 wf[3][P][2];
  bf16x8 af[3][2][2];

  auto LD = [&](int buf, int pr) {
    int k0 = ksb + pr * 2;
    #pragma unroll
    for (int p = 0; p < P; p++) {
      wf[buf][p][0] = ldb8(wb + (size_t)p * PS_HID + (size_t)k0 * 512);
      wf[buf][p][1] = ldb8(wb + (size_t)p * PS_HID + (size_t)(k0 + 1) * 512);
    }
    af[buf][0][0] = ldb8(a0 + k0 * 32);       af[buf][1][0] = ldb8(a1 + k0 * 32);
    af[buf][0][1] = ldb8(a0 + (k0 + 1) * 32); af[buf][1][1] = ldb8(a1 + (k0 + 1) * 32);
  };
  auto CP = [&](int buf) {
    #pragma unroll
    for (int p = 0; p < P; p++) {
      c0a = mf(af[buf][0][0], wf[buf][p][0], c0a); c1a = mf(af[buf][1][0], wf[buf][p][0], c1a);
      c0b = mf(af[buf][0][1], wf[buf][p][1], c0b); c1b = mf(af[buf][1][1], wf[buf][p][1], c1b);
    }
  };

  LD(0, 0); LD(1, 1); LD(2, 2);
  #pragma unroll
  for (int i = 0; i < NP; i++) {              // full unroll -> static buf index
    CP(i % 3);
    if (i + 3 < NP) LD(i % 3, i + 3);
  }

  f32x4 acc0 = c0a + c0b, acc1 = c1a + c1b;

  if (kh == 1) {
    #pragma unroll
    for (int r = 0; r < 4; r++) {
      red[wid - 4][lane * 8 + r]     = acc0[r];
      red[wid - 4][lane * 8 + 4 + r] = acc1[r];
    }
  }
  __syncthreads();
  if (kh == 0) {
    int jc = nt * 32 + jf * 16 + r15;
    float bj = bias[jc];
    #pragma unroll
    for (int r = 0; r < 4; r++) {
      float v0 = acc0[r] + red[wid][lane * 8 + r]     + bj;
      float v1 = acc1[r] + red[wid][lane * 8 + 4 + r] + bj;
      int br0 = mt * 64 + mfh * 32 + g * 4 + r;     // C/D: row=(lane>>4)*4+r, col=lane&15
      lif_store(v0, mem, (size_t)br0 * HID + jc, spk_out);
      lif_store(v1, mem, (size_t)(br0 + 16) * HID + jc, spk_out);
    }
  }
  __syncthreads();   // red reusable by next phase within this block
}

// --------------------------- input-layer phase ---------------------------
__device__ __forceinline__ void load_split(const float* __restrict__ ar, int k0,
                                           bf16x8& dh, bf16x8& dl) {
  float x[8];
  if (k0 + 7 < INDIM) {
    float4 v0 = *reinterpret_cast<const float4*>(ar + k0);
    float4 v1 = *reinterpret_cast<const float4*>(ar + k0 + 4);
    x[0]=v0.x; x[1]=v0.y; x[2]=v0.z; x[3]=v0.w;
    x[4]=v1.x; x[5]=v1.y; x[6]=v1.z; x[7]=v1.w;
  } else {
    #pragma unroll
    for (int e = 0; e < 8; e++) x[e] = (k0 + e < INDIM) ? ar[k0 + e] : 0.0f;
  }
  #pragma unroll
  for (int e = 0; e < 8; e++) {
    __bf16 h = (__bf16)x[e];
    dh[e] = h;
    dl[e] = (__bf16)(x[e] - (float)h);
  }
}

template<int P>
__device__ __forceinline__ void phase_in(
    int bid, int tid, const float* __restrict__ A, const u16* __restrict__ Wf,
    const float* __restrict__ bias, float* __restrict__ mem,
    u16* __restrict__ spk_out, float (&red)[8][512]) {
  constexpr int PL = (P < 3) ? P : 2;   // dl pairs with wh,wm only (dl*wl <= 2^-27)
  int mt = bid >> 6, nt = bid & 63;
  int wid = tid >> 6, lane = tid & 63;
  int r15 = lane & 15, g = lane >> 4;
  int jf = wid & 1, mfh = (wid >> 1) & 1, kh = wid >> 2;
  const int ksb = kh ? 12 : 0;          // K halves: 12 + 10 k-steps
  const int np  = kh ? 5 : 6;

  const u16* wb = Wf + ((size_t)(nt * 2 + jf) * KS_IN) * 512 + (size_t)lane * 8;
  const float* a0 = A + (size_t)(mt * 64 + mfh * 32 + r15) * INDIM;
  const float* a1 = a0 + 16 * INDIM;

  f32x4 c0a{}, c1a{}, c0b{}, c1b{};
  bf16x8 wU0[P], wU1[P], wV0[P], wV1[P];
  bf16x8 hU00, hU01, hU10, hU11, lU00, lU01, lU10, lU11;
  bf16x8 hV00, hV01, hV10, hV11, lV00, lV01, lV10, lV11;

  auto loadU = [&](int pr) {
    int ks = ksb + pr * 2;
    int k0 = ks * 32 + g * 8;
    #pragma unroll
    for (int p = 0; p < P; p++) {
      wU0[p] = ldb8(wb + (size_t)p * PS_IN + (size_t)ks * 512);
      wU1[p] = ldb8(wb + (size_t)p * PS_IN + (size_t)(ks + 1) * 512);
    }
    load_split(a0, k0, hU00, lU00);      load_split(a1, k0, hU10, lU10);
    load_split(a0, k0 + 32, hU01, lU01); load_split(a1, k0 + 32, hU11, lU11);
  };
  auto loadV = [&](int pr) {
    int ks = ksb + pr * 2;
    int k0 = ks * 32 + g * 8;
    #pragma unroll
    for (int p = 0; p < P; p++) {
      wV0[p] = ldb8(wb + (size_t)p * PS_IN + (size_t)ks * 512);
      wV1[p] = ldb8(wb + (size_t)p * PS_IN + (size_t)(ks + 1) * 512);
    }
    load_split(a0, k0, hV00, lV00);      load_split(a1, k0, hV10, lV10);
    load_split(a0, k0 + 32, hV01, lV01); load_split(a1, k0 + 32, hV11, lV11);
  };
  auto compU = [&]() {
    #pragma unroll
    for (int p = 0; p < P; p++) {
      c0a = mf(hU00, wU0[p], c0a); c1a = mf(hU10, wU0[p], c1a);
      c0b = mf(hU01, wU1[p], c0b); c1b = mf(hU11, wU1[p], c1b);
    }
    #pragma unroll
    for (int p = 0; p < PL; p++) {
      c0a = mf(lU00, wU0[p], c0a); c1a = mf(lU10, wU0[p], c1a);
      c0b = mf(lU01, wU1[p], c0b); c1b = mf(lU11, wU1[p], c1b);
    }
  };
  auto compV = [&]() {
    #pragma unroll
    for (int p = 0; p < P; p++) {
      c0a = mf(hV00, wV0[p], c0a); c1a = mf(hV10, wV0[p], c1a);
      c0b = mf(hV01, wV1[p], c0b); c1b = mf(hV11, wV1[p], c1b);
    }
    #pragma unroll
    for (int p = 0; p < PL; p++) {
      c0a = mf(lV00, wV0[p], c0a); c1a = mf(lV10, wV0[p], c1a);
      c0b = mf(lV01, wV1[p], c0b); c1b = mf(lV11, wV1[p], c1b);
    }
  };

  loadU(0);
  if (np > 1) loadV(1);
  int i = 0;
  for (; i + 2 < np; i += 2) {
    compU(); loadU(i + 2);
    compV(); if (i + 3 < np) loadV(i + 3);
  }
  compU();
  if (i + 1 < np) compV();

  f32x4 acc0 = c0a + c0b, acc1 = c1a + c1b;

  if (kh == 1) {
    #pragma unroll
    for (int r = 0; r < 4; r++) {
      red[wid - 4][lane * 8 + r]     = acc0[r];
      red[wid - 4][lane * 8 + 4 + r] = acc1[r];
    }
  }
  __syncthreads();
  if (kh == 0) {
    int jc = nt * 32 + jf * 16 + r15;
    float bj = bias[jc];
    #pragma unroll
    for (int r = 0; r < 4; r++) {
      float v0 = acc0[r] + red[wid][lane * 8 + r]     + bj;
      float v1 = acc1[r] + red[wid][lane * 8 + 4 + r] + bj;
      int br0 = mt * 64 + mfh * 32 + g * 4 + r;
      lif_store(v0, mem, (size_t)br0 * HID + jc, spk_out);
      lif_store(v1, mem, (size_t)(br0 + 16) * HID + jc, spk_out);
    }
  }
  __syncthreads();
}

// --------------------------- output-layer phase ---------------------------
// blocks 0..15: rows 16*bid..+16, cols 0..31 (padded). 8 waves split K (8 k-steps each).
template<int P>
__device__ __forceinline__ void phase_out(
    int bid, int tid, const u16* __restrict__ A, const u16* __restrict__ Wf,
    const float* __restrict__ bias, float* __restrict__ mem4,
    float* __restrict__ outp, float (&red)[8][512]) {
  int wid = tid >> 6, lane = tid & 63;
  int r15 = lane & 15, g = lane >> 4;
  const u16* a0 = A + (size_t)(bid * 16 + r15) * HID + g * 8;

  f32x4 acc0{}, acc1{};
  #pragma unroll
  for (int kk = 0; kk < 8; kk++) {
    int ks = wid * 8 + kk;
    bf16x8 av = ldb8(a0 + ks * 32);
    #pragma unroll
    for (int p = 0; p < P; p++) {
      acc0 = mf(av, ldb8(Wf + (size_t)p * PS_OUT + (size_t)ks * 512 + (size_t)lane * 8), acc0);
      acc1 = mf(av, ldb8(Wf + (size_t)p * PS_OUT + (size_t)(KS_HID + ks) * 512 + (size_t)lane * 8), acc1);
    }
  }

  #pragma unroll
  for (int r = 0; r < 4; r++) {
    red[wid][lane * 8 + r]     = acc0[r];
    red[wid][lane * 8 + 4 + r] = acc1[r];
  }
  __syncthreads();
  if (wid == 0) {
    #pragma unroll
    for (int h = 0; h < 2; h++) {
      int jc = h * 16 + r15;
      float bj = (jc < ODIM) ? bias[jc] : 0.0f;
      #pragma unroll
      for (int r = 0; r < 4; r++) {
        float v = bj;
        #pragma unroll
        for (int w = 0; w < 8; w++) v += red[w][lane * 8 + h * 4 + r];
        int br = bid * 16 + g * 4 + r;
        size_t midx = (size_t)br * 32 + jc;
        float mo = mem4[midx];
        float mn = 0.9f * mo + v - ((mo > 1.0f) ? 1.0f : 0.0f);
        mem4[midx] = mn;
        if (jc < ODIM) outp[(size_t)br * ODIM + jc] = (mn - 1.0f > 0.0f) ? 1.0f : 0.0f;
      }
    }
  }
  __syncthreads();
}

// --------------------------- persistent kernel ---------------------------
struct KArgs {
  const float* data;
  const u16 *w0, *w1, *w2, *w3, *w4;
  const float *b0, *b1, *b2, *b3, *b4;
  float *mem0, *mem1, *mem2, *mem3, *mem4;
  u16 *spk0, *spk1, *spk2, *spk3;
  float* out;
};

template<int P>
__global__ __launch_bounds__(512, 2) void k_all(KArgs a) {
  cg::grid_group gg = cg::this_grid();
  __shared__ float red[8][512];
  int bid = blockIdx.x, tid = threadIdx.x;

  for (int t = 0; t < TSTEPS; t++) {
    phase_in<P>(bid, tid, a.data + (size_t)t * BATCH * INDIM, a.w0, a.b0,
                a.mem0, a.spk0, red);
    if (t > 0 && bid < 16)
      phase_out<P>(bid, tid, a.spk3, a.w4, a.b4, a.mem4,
                   a.out + (size_t)(t - 1) * BATCH * ODIM, red);
    gg.sync();
    phase_hid<P>(bid, tid, a.spk0, a.w1, a.b1, a.mem1, a.spk1, red);
    gg.sync();
    phase_hid<P>(bid, tid, a.spk1, a.w2, a.b2, a.mem2, a.spk2, red);
    gg.sync();
    phase_hid<P>(bid, tid, a.spk2, a.w3, a.b3, a.mem3, a.spk3, red);
    gg.sync();
  }
  if (bid < 16)
    phase_out<P>(bid, tid, a.spk3, a.w4, a.b4, a.mem4,
                 a.out + (size_t)(TSTEPS - 1) * BATCH * ODIM, red);
}

// ------------------------------ host ------------------------------
template<int P>
static void launch_all(const KArgs& ka,
                       const float* W0, const float* W1, const float* W2,
                       const float* W3, const float* W4, hipStream_t s) {
  int n4 = (4 * BATCH * HID + BATCH * 32) / 4;
  k_zero<<<dim3(1024), dim3(256), 0, s>>>((float4*)ka.mem0, n4);

  int nc0 = JT_HID * KS_IN * 64;
  k_split<<<dim3(nc0 / 256), dim3(256), 0, s>>>(W0, (u16*)ka.w0, HID, INDIM, KS_IN, nc0, P, PS_IN);
  int nch = JT_HID * KS_HID * 64;
  k_split<<<dim3(nch / 256), dim3(256), 0, s>>>(W1, (u16*)ka.w1, HID, HID, KS_HID, nch, P, PS_HID);
  k_split<<<dim3(nch / 256), dim3(256), 0, s>>>(W2, (u16*)ka.w2, HID, HID, KS_HID, nch, P, PS_HID);
  k_split<<<dim3(nch / 256), dim3(256), 0, s>>>(W3, (u16*)ka.w3, HID, HID, KS_HID, nch, P, PS_HID);
  int nc4 = 2 * KS_HID * 64;
  k_split<<<dim3(nc4 / 256), dim3(256), 0, s>>>(W4, (u16*)ka.w4, ODIM, HID, KS_HID, nc4, P, PS_OUT);

  KArgs args = ka;
  void* kp[] = { &args };
  hipLaunchCooperativeKernel(reinterpret_cast<const void*>(&k_all<P>),
                             dim3(256), dim3(512), kp, 0, s);
}

extern "C" void kernel_launch(void* const* d_in, const int* in_sizes, int n_in,
                              void* d_out, int out_size, void* d_ws, size_t ws_size,
                              hipStream_t stream) {
  (void)in_sizes; (void)n_in; (void)out_size;
  const float* data = (const float*)d_in[0];
  const float* W0 = (const float*)d_in[1];  const float* b0 = (const float*)d_in[2];
  const float* W1 = (const float*)d_in[3];  const float* b1 = (const float*)d_in[4];
  const float* W2 = (const float*)d_in[5];  const float* b2 = (const float*)d_in[6];
  const float* W3 = (const float*)d_in[7];  const float* b3 = (const float*)d_in[8];
  const float* W4 = (const float*)d_in[9];  const float* b4 = (const float*)d_in[10];

  uint8_t* ws = (uint8_t*)d_ws;
  size_t off = 0;
  auto take = [&](size_t bytes) -> uint8_t* { uint8_t* r = ws + off; off += bytes; return r; };

  KArgs ka;
  ka.data = data;
  ka.b0 = b0; ka.b1 = b1; ka.b2 = b2; ka.b3 = b3; ka.b4 = b4;
  ka.out = (float*)d_out;

  ka.mem0 = (float*)take((size_t)BATCH * HID * 4);
  ka.mem1 = (float*)take((size_t)BATCH * HID * 4);
  ka.mem2 = (float*)take((size_t)BATCH * HID * 4);
  ka.mem3 = (float*)take((size_t)BATCH * HID * 4);
  ka.mem4 = (float*)take((size_t)BATCH * 32 * 4);
  ka.spk0 = (u16*)take((size_t)BATCH * HID * 2);
  ka.spk1 = (u16*)take((size_t)BATCH * HID * 2);
  ka.spk2 = (u16*)take((size_t)BATCH * HID * 2);
  ka.spk3 = (u16*)take((size_t)BATCH * HID * 2);

  size_t fixed = off;
  size_t per_set = 2 * (PS_IN + 3 * PS_HID + PS_OUT);   // bytes per plane-set
  int P = 3;
  if (fixed + 3 * per_set > ws_size) P = 2;
  if (fixed + 2 * per_set > ws_size) P = 1;

  ka.w0 = (u16*)take((size_t)P * PS_IN * 2);
  ka.w1 = (u16*)take((size_t)P * PS_HID * 2);
  ka.w2 = (u16*)take((size_t)P * PS_HID * 2);
  ka.w3 = (u16*)take((size_t)P * PS_HID * 2);
  ka.w4 = (u16*)take((size_t)P * PS_OUT * 2);

  if (P == 3)      launch_all<3>(ka, W0, W1, W2, W3, W4, stream);
  else if (P == 2) launch_all<2>(ka, W0, W1, W2, W3, W4, stream);
  else             launch_all<1>(ka, W0, W1, W2, W3, W4, stream);
}

// Round 7
// 23098.660 us; speedup vs baseline: 1.9948x; 1.9948x over previous
//
#include <hip/hip_runtime.h>
#include <stdint.h>

typedef unsigned short u16;
typedef unsigned long long u64;
typedef __bf16 bf16x8 __attribute__((ext_vector_type(8)));
typedef u16    u16x8  __attribute__((ext_vector_type(8)));
typedef float  f32x4  __attribute__((ext_vector_type(4)));

#define TSTEPS 100
#define BATCH  256
#define INDIM  700
#define HID    2048
#define ODIM   20

#define KS_IN  22            // ceil(700/32)
#define KS_HID 64            // 2048/32
#define JT_HID 128           // 2048/16
#define PS_IN  ((size_t)JT_HID*KS_IN*512)    // elems per plane (L0)
#define PS_HID ((size_t)JT_HID*KS_HID*512)   // elems per plane (hidden)
#define PS_OUT ((size_t)2*KS_HID*512)        // elems per plane (L4, N padded to 32)

__device__ __forceinline__ bf16x8 ldb8(const u16* p) {
  return *reinterpret_cast<const bf16x8*>(p);
}
__device__ __forceinline__ f32x4 mf(bf16x8 a, bf16x8 b, f32x4 c) {
  return __builtin_amdgcn_mfma_f32_16x16x32_bf16(a, b, c, 0, 0, 0);
}

// ---------------- shared memory ----------------
struct Shm {
  float red[8][512];      // 16 KB  cross-wave reduce
  u16 lpk[128 * 66];      // 16.5KB staged packed panel [chunk][row(64)+pad]
  u16 lpk4[128 * 18];     // 4.5KB  staged packed panel for L4 [chunk][row(16)+pad]
  u16 lut[256 * 8];       // 4 KB   byte -> bf16x8 {0,1} expansion LUT
};

__device__ __forceinline__ bf16x8 lutv(const Shm& sh, int b) {
  return *reinterpret_cast<const bf16x8*>(&sh.lut[b * 8]);
}

// ---------------- custom grid barrier (no L2 invalidate) ----------------
// sc1 (agent-scope) relaxed atomics operate at the L3 coherence point and do
// NOT writeback/invalidate per-XCD L2 -> weights stay L2-resident across all
// 400 barriers. __syncthreads drains each wave's vmcnt before s_barrier, so
// all prior sc1 stores are globally visible before tid0 signals arrival.
__device__ __forceinline__ void gridbar(unsigned int* cnt, unsigned int epoch) {
  __syncthreads();
  if (threadIdx.x == 0) {
    __hip_atomic_fetch_add(cnt, 1u, __ATOMIC_RELAXED, __HIP_MEMORY_SCOPE_AGENT);
    unsigned target = epoch * 256u;
    int spins = 0;
    while (__hip_atomic_load(cnt, __ATOMIC_RELAXED, __HIP_MEMORY_SCOPE_AGENT) < target) {
      __builtin_amdgcn_s_sleep(2);
      if (++spins > (1 << 20)) break;   // failsafe: terminate (wrong) rather than hang
    }
  }
  __syncthreads();
}

// ------------------------------ init ------------------------------
__global__ void k_zero(float4* __restrict__ p, int n4) {
  int i = blockIdx.x * 256 + threadIdx.x;
  int s = gridDim.x * 256;
  float4 z; z.x = 0.f; z.y = 0.f; z.z = 0.f; z.w = 0.f;
  for (; i < n4; i += s) p[i] = z;
}

// -------------------- weight split into fragment layout --------------------
__global__ void k_split(const float* __restrict__ W, u16* __restrict__ outp,
                        int N, int K, int KS, int nchunks, int planes, size_t ps) {
  int c = blockIdx.x * 256 + threadIdx.x;
  if (c >= nchunks) return;
  int lane = c & 63;
  int t  = c >> 6;
  int ks = t % KS;
  int jt = t / KS;
  int j  = jt * 16 + (lane & 15);
  int k0 = ks * 32 + ((lane >> 4) << 3);
  float x[8];
  if (j < N) {
    const float* wr = W + (size_t)j * K;
    if (k0 + 7 < K) {
      float4 v0 = *reinterpret_cast<const float4*>(wr + k0);
      float4 v1 = *reinterpret_cast<const float4*>(wr + k0 + 4);
      x[0]=v0.x; x[1]=v0.y; x[2]=v0.z; x[3]=v0.w;
      x[4]=v1.x; x[5]=v1.y; x[6]=v1.z; x[7]=v1.w;
    } else {
      #pragma unroll
      for (int e = 0; e < 8; e++) x[e] = (k0 + e < K) ? wr[k0 + e] : 0.0f;
    }
  } else {
    #pragma unroll
    for (int e = 0; e < 8; e++) x[e] = 0.0f;
  }
  u16x8 vh, vm, vl;
  #pragma unroll
  for (int e = 0; e < 8; e++) {
    float w   = x[e];
    __bf16 bh = (__bf16)w;
    float r1  = w - (float)bh;
    __bf16 bm = (__bf16)r1;
    __bf16 bl = (__bf16)(r1 - (float)bm);
    vh[e] = __builtin_bit_cast(unsigned short, bh);
    vm[e] = __builtin_bit_cast(unsigned short, bm);
    vl[e] = __builtin_bit_cast(unsigned short, bl);
  }
  size_t base = (size_t)c * 8;
  *reinterpret_cast<u16x8*>(outp + base) = vh;
  if (planes > 1) *reinterpret_cast<u16x8*>(outp + ps     + base) = vm;
  if (planes > 2) *reinterpret_cast<u16x8*>(outp + 2 * ps + base) = vl;
}

// ------------------- LIF + ballot-pack epilogue (hidden/input) -------------------
// Packed layout pkT[chunk c(128)][row(256)] u16 ; bit b of chunk c = col c*16+b.
// Stored as u64 covering 4 consecutive rows' u16 slices.
__device__ __forceinline__ void lif_pack_store(
    f32x4 s0, f32x4 s1, float bj, int mt, int nt, int jf, int mfh,
    int r15, int g, float* __restrict__ mem, u64* __restrict__ pkOut) {
  u64 p0 = 0, p1 = 0;
  #pragma unroll
  for (int r = 0; r < 4; r++) {
    int br0 = mt * 64 + mfh * 32 + g * 4 + r;     // C/D: row=(lane>>4)*4+r, col=lane&15
    int jc  = nt * 32 + jf * 16 + r15;
    size_t i0 = (size_t)br0 * HID + jc;
    size_t i1 = (size_t)(br0 + 16) * HID + jc;
    float mo0 = mem[i0];
    float mn0 = 0.9f * mo0 + (s0[r] + bj) - ((mo0 > 1.0f) ? 1.0f : 0.0f);
    mem[i0] = mn0;
    float mo1 = mem[i1];
    float mn1 = 0.9f * mo1 + (s1[r] + bj) - ((mo1 > 1.0f) ? 1.0f : 0.0f);
    mem[i1] = mn1;
    u64 b0 = __ballot((mn0 - 1.0f) > 0.0f);       // bit(lane)=bit(g*16+r15)
    u64 b1 = __ballot((mn1 - 1.0f) > 0.0f);
    if (r15 < 4) {                                 // slice for g'=r15 -> row base+r15*4+r
      p0 |= (u64)((b0 >> (16 * r15)) & 0xFFFFull) << (16 * r);
      p1 |= (u64)((b1 >> (16 * r15)) & 0xFFFFull) << (16 * r);
    }
  }
  if (r15 < 4 && g == 0) {
    int chunk = nt * 2 + jf;
    int rb = (mt * 64 + mfh * 32) >> 2;            // u64 row-index base
    __hip_atomic_store(&pkOut[(size_t)chunk * 64 + rb + r15], p0,
                       __ATOMIC_RELAXED, __HIP_MEMORY_SCOPE_AGENT);
    __hip_atomic_store(&pkOut[(size_t)chunk * 64 + rb + 4 + r15], p1,
                       __ATOMIC_RELAXED, __HIP_MEMORY_SCOPE_AGENT);
  }
}

// --------------------------- hidden-layer phase ---------------------------
// 256 blocks = 4 mt x 64 nt. 8 waves (jf, mfh, kh). A comes from bit-packed
// spikes: LDS-staged panel + LUT expansion. W: plain loads (L2-resident).
template<int P>
__device__ __forceinline__ void phase_hid(
    int bid, int tid, const u64* __restrict__ pkIn, u64* __restrict__ pkOut,
    const u16* __restrict__ Wf, const float* __restrict__ bias,
    float* __restrict__ mem, Shm& sh) {
  int mt = bid >> 6, nt = bid & 63;
  int wid = tid >> 6, lane = tid & 63;
  int r15 = lane & 15, g = lane >> 4;
  int jf = wid & 1, mfh = (wid >> 1) & 1, kh = wid >> 2;
  const int ksb = kh * 32;

  // stage packed A panel (rows mt*64..+64, all 2048 bits) -> 16 KB LDS
  #pragma unroll
  for (int q = 0; q < 4; q++) {
    int f = q * 512 + tid;
    int c = f >> 4, rv = f & 15;
    u64 v = __hip_atomic_load((u64*)&pkIn[(size_t)c * 64 + mt * 16 + rv],
                              __ATOMIC_RELAXED, __HIP_MEMORY_SCOPE_AGENT);
    int rb = rv * 4;
    sh.lpk[c * 66 + rb]     = (u16)(v);
    sh.lpk[c * 66 + rb + 1] = (u16)(v >> 16);
    sh.lpk[c * 66 + rb + 2] = (u16)(v >> 32);
    sh.lpk[c * 66 + rb + 3] = (u16)(v >> 48);
  }
  __syncthreads();

  const u16* wb = Wf + ((size_t)(nt * 2 + jf) * KS_HID) * 512 + (size_t)lane * 8;
  int row0 = mfh * 32 + r15, row1 = row0 + 16;
  int ghalf = g >> 1, gsh = (g & 1) * 8;

  f32x4 c0a{}, c1a{}, c0b{}, c1b{};
  bf16x8 wf_[3][P][2];

  auto LDW = [&](int buf, int pr) {
    int k0 = ksb + pr * 2;
    #pragma unroll
    for (int p = 0; p < P; p++) {
      wf_[buf][p][0] = ldb8(wb + (size_t)p * PS_HID + (size_t)k0 * 512);
      wf_[buf][p][1] = ldb8(wb + (size_t)p * PS_HID + (size_t)(k0 + 1) * 512);
    }
  };
  auto IDX = [&](int pr, int& o0, int& o1, int& o2, int& o3) {
    int ks0 = ksb + pr * 2;
    int c00 = ks0 * 2 + ghalf;     // byte (ks0*4+g) lives in u16 chunk ks0*2+(g>>1)
    int c01 = c00 + 2;             // ks0+1
    int v00 = sh.lpk[c00 * 66 + row0];
    int v01 = sh.lpk[c01 * 66 + row0];
    int v10 = sh.lpk[c00 * 66 + row1];
    int v11 = sh.lpk[c01 * 66 + row1];
    o0 = (v00 >> gsh) & 0xFF;
    o1 = (v01 >> gsh) & 0xFF;
    o2 = (v10 >> gsh) & 0xFF;
    o3 = (v11 >> gsh) & 0xFF;
  };

  LDW(0, 0); LDW(1, 1); LDW(2, 2);
  int b0, b1, b2, b3, n0, n1, n2, n3;
  IDX(0, b0, b1, b2, b3);
  #pragma unroll
  for (int pr = 0; pr < 16; pr++) {
    if (pr + 1 < 16) IDX(pr + 1, n0, n1, n2, n3);
    bf16x8 a0 = lutv(sh, b0), a1 = lutv(sh, b1), a2 = lutv(sh, b2), a3 = lutv(sh, b3);
    int buf = pr % 3;
    #pragma unroll
    for (int p = 0; p < P; p++) {
      c0a = mf(a0, wf_[buf][p][0], c0a);
      c1a = mf(a2, wf_[buf][p][0], c1a);
      c0b = mf(a1, wf_[buf][p][1], c0b);
      c1b = mf(a3, wf_[buf][p][1], c1b);
    }
    if (pr + 3 < 16) LDW(buf, pr + 3);
    b0 = n0; b1 = n1; b2 = n2; b3 = n3;
  }

  f32x4 acc0 = c0a + c0b, acc1 = c1a + c1b;

  if (kh == 1) {
    #pragma unroll
    for (int r = 0; r < 4; r++) {
      sh.red[wid - 4][lane * 8 + r]     = acc0[r];
      sh.red[wid - 4][lane * 8 + 4 + r] = acc1[r];
    }
  }
  __syncthreads();
  if (kh == 0) {
    float bj = bias[nt * 32 + jf * 16 + r15];
    f32x4 s0, s1;
    #pragma unroll
    for (int r = 0; r < 4; r++) {
      s0[r] = acc0[r] + sh.red[wid][lane * 8 + r];
      s1[r] = acc1[r] + sh.red[wid][lane * 8 + 4 + r];
    }
    lif_pack_store(s0, s1, bj, mt, nt, jf, mfh, r15, g, mem, pkOut);
  }
  __syncthreads();
}

// --------------------------- input-layer phase ---------------------------
__device__ __forceinline__ void load_split(const float* __restrict__ ar, int k0,
                                           bf16x8& dh, bf16x8& dl) {
  float x[8];
  if (k0 + 7 < INDIM) {
    float4 v0 = *reinterpret_cast<const float4*>(ar + k0);
    float4 v1 = *reinterpret_cast<const float4*>(ar + k0 + 4);
    x[0]=v0.x; x[1]=v0.y; x[2]=v0.z; x[3]=v0.w;
    x[4]=v1.x; x[5]=v1.y; x[6]=v1.z; x[7]=v1.w;
  } else {
    #pragma unroll
    for (int e = 0; e < 8; e++) x[e] = (k0 + e < INDIM) ? ar[k0 + e] : 0.0f;
  }
  #pragma unroll
  for (int e = 0; e < 8; e++) {
    __bf16 h = (__bf16)x[e];
    dh[e] = h;
    dl[e] = (__bf16)(x[e] - (float)h);
  }
}

template<int P>
__device__ __forceinline__ void phase_in(
    int bid, int tid, const float* __restrict__ A, const u16* __restrict__ Wf,
    const float* __restrict__ bias, float* __restrict__ mem,
    u64* __restrict__ pkOut, Shm& sh) {
  constexpr int PL = (P < 3) ? P : 2;   // dl pairs with wh,wm only (dl*wl <= 2^-27)
  int mt = bid >> 6, nt = bid & 63;
  int wid = tid >> 6, lane = tid & 63;
  int r15 = lane & 15, g = lane >> 4;
  int jf = wid & 1, mfh = (wid >> 1) & 1, kh = wid >> 2;
  const int ksb = kh ? 12 : 0;          // K halves: 12 + 10 k-steps
  const int np  = kh ? 5 : 6;

  const u16* wb = Wf + ((size_t)(nt * 2 + jf) * KS_IN) * 512 + (size_t)lane * 8;
  const float* a0 = A + (size_t)(mt * 64 + mfh * 32 + r15) * INDIM;
  const float* a1 = a0 + 16 * INDIM;

  f32x4 c0a{}, c1a{}, c0b{}, c1b{};
  bf16x8 wU0[P], wU1[P], wV0[P], wV1[P];
  bf16x8 hU00, hU01, hU10, hU11, lU00, lU01, lU10, lU11;
  bf16x8 hV00, hV01, hV10, hV11, lV00, lV01, lV10, lV11;

  auto loadU = [&](int pr) {
    int ks = ksb + pr * 2;
    int k0 = ks * 32 + g * 8;
    #pragma unroll
    for (int p = 0; p < P; p++) {
      wU0[p] = ldb8(wb + (size_t)p * PS_IN + (size_t)ks * 512);
      wU1[p] = ldb8(wb + (size_t)p * PS_IN + (size_t)(ks + 1) * 512);
    }
    load_split(a0, k0, hU00, lU00);      load_split(a1, k0, hU10, lU10);
    load_split(a0, k0 + 32, hU01, lU01); load_split(a1, k0 + 32, hU11, lU11);
  };
  auto loadV = [&](int pr) {
    int ks = ksb + pr * 2;
    int k0 = ks * 32 + g * 8;
    #pragma unroll
    for (int p = 0; p < P; p++) {
      wV0[p] = ldb8(wb + (size_t)p * PS_IN + (size_t)ks * 512);
      wV1[p] = ldb8(wb + (size_t)p * PS_IN + (size_t)(ks + 1) * 512);
    }
    load_split(a0, k0, hV00, lV00);      load_split(a1, k0, hV10, lV10);
    load_split(a0, k0 + 32, hV01, lV01); load_split(a1, k0 + 32, hV11, lV11);
  };
  auto compU = [&]() {
    #pragma unroll
    for (int p = 0; p < P; p++) {
      c0a = mf(hU00, wU0[p], c0a); c1a = mf(hU10, wU0[p], c1a);
      c0b = mf(hU01, wU1[p], c0b); c1b = mf(hU11, wU1[p], c1b);
    }
    #pragma unroll
    for (int p = 0; p < PL; p++) {
      c0a = mf(lU00, wU0[p], c0a); c1a = mf(lU10, wU0[p], c1a);
      c0b = mf(lU01, wU1[p], c0b); c1b = mf(lU11, wU1[p], c1b);
    }
  };
  auto compV = [&]() {
    #pragma unroll
    for (int p = 0; p < P; p++) {
      c0a = mf(hV00, wV0[p], c0a); c1a = mf(hV10, wV0[p], c1a);
      c0b = mf(hV01, wV1[p], c0b); c1b = mf(hV11, wV1[p], c1b);
    }
    #pragma unroll
    for (int p = 0; p < PL; p++) {
      c0a = mf(lV00, wV0[p], c0a); c1a = mf(lV10, wV0[p], c1a);
      c0b = mf(lV01, wV1[p], c0b); c1b = mf(lV11, wV1[p], c1b);
    }
  };

  loadU(0);
  if (np > 1) loadV(1);
  int i = 0;
  for (; i + 2 < np; i += 2) {
    compU(); loadU(i + 2);
    compV(); if (i + 3 < np) loadV(i + 3);
  }
  compU();
  if (i + 1 < np) compV();

  f32x4 acc0 = c0a + c0b, acc1 = c1a + c1b;

  if (kh == 1) {
    #pragma unroll
    for (int r = 0; r < 4; r++) {
      sh.red[wid - 4][lane * 8 + r]     = acc0[r];
      sh.red[wid - 4][lane * 8 + 4 + r] = acc1[r];
    }
  }
  __syncthreads();
  if (kh == 0) {
    float bj = bias[nt * 32 + jf * 16 + r15];
    f32x4 s0, s1;
    #pragma unroll
    for (int r = 0; r < 4; r++) {
      s0[r] = acc0[r] + sh.red[wid][lane * 8 + r];
      s1[r] = acc1[r] + sh.red[wid][lane * 8 + 4 + r];
    }
    lif_pack_store(s0, s1, bj, mt, nt, jf, mfh, r15, g, mem, pkOut);
  }
  __syncthreads();
}

// --------------------------- output-layer phase ---------------------------
template<int P>
__device__ __forceinline__ void phase_out(
    int bid, int tid, const u64* __restrict__ pkIn, const u16* __restrict__ Wf,
    const float* __restrict__ bias, float* __restrict__ mem4,
    float* __restrict__ outp, Shm& sh) {
  int wid = tid >> 6, lane = tid & 63;
  int r15 = lane & 15, g = lane >> 4;
  int ghalf = g >> 1, gsh = (g & 1) * 8;

  // stage 16 rows of packed spikes (4 KB)
  {
    int c = tid >> 2, rv = tid & 3;
    u64 v = __hip_atomic_load((u64*)&pkIn[(size_t)c * 64 + bid * 4 + rv],
                              __ATOMIC_RELAXED, __HIP_MEMORY_SCOPE_AGENT);
    int rb = rv * 4;
    sh.lpk4[c * 18 + rb]     = (u16)(v);
    sh.lpk4[c * 18 + rb + 1] = (u16)(v >> 16);
    sh.lpk4[c * 18 + rb + 2] = (u16)(v >> 32);
    sh.lpk4[c * 18 + rb + 3] = (u16)(v >> 48);
  }
  __syncthreads();

  f32x4 acc0{}, acc1{};
  #pragma unroll
  for (int kk = 0; kk < 8; kk++) {
    int ks = wid * 8 + kk;
    int cc = ks * 2 + ghalf;
    int v = sh.lpk4[cc * 18 + r15];
    bf16x8 av = lutv(sh, (v >> gsh) & 0xFF);
    #pragma unroll
    for (int p = 0; p < P; p++) {
      acc0 = mf(av, ldb8(Wf + (size_t)p * PS_OUT + (size_t)ks * 512 + (size_t)lane * 8), acc0);
      acc1 = mf(av, ldb8(Wf + (size_t)p * PS_OUT + (size_t)(KS_HID + ks) * 512 + (size_t)lane * 8), acc1);
    }
  }

  #pragma unroll
  for (int r = 0; r < 4; r++) {
    sh.red[wid][lane * 8 + r]     = acc0[r];
    sh.red[wid][lane * 8 + 4 + r] = acc1[r];
  }
  __syncthreads();
  if (wid == 0) {
    #pragma unroll
    for (int h = 0; h < 2; h++) {
      int jc = h * 16 + r15;
      float bj = (jc < ODIM) ? bias[jc] : 0.0f;
      #pragma unroll
      for (int r = 0; r < 4; r++) {
        float v = bj;
        #pragma unroll
        for (int w = 0; w < 8; w++) v += sh.red[w][lane * 8 + h * 4 + r];
        int br = bid * 16 + g * 4 + r;
        size_t midx = (size_t)br * 32 + jc;
        float mo = mem4[midx];
        float mn = 0.9f * mo + v - ((mo > 1.0f) ? 1.0f : 0.0f);
        mem4[midx] = mn;
        if (jc < ODIM) outp[(size_t)br * ODIM + jc] = (mn - 1.0f > 0.0f) ? 1.0f : 0.0f;
      }
    }
  }
  __syncthreads();
}

// --------------------------- persistent kernel ---------------------------
struct KArgs {
  const float* data;
  const u16 *w0, *w1, *w2, *w3, *w4;
  const float *b0, *b1, *b2, *b3, *b4;
  float *mem0, *mem1, *mem2, *mem3, *mem4;
  u64 *pk0, *pk1, *pk2, *pk3;
  unsigned int* cnt;
  float* out;
};

template<int P>
__global__ __launch_bounds__(512, 2) void k_all(KArgs a) {
  __shared__ Shm sh;
  int bid = blockIdx.x, tid = threadIdx.x;

  if (tid < 256) {
    #pragma unroll
    for (int e = 0; e < 8; e++)
      sh.lut[tid * 8 + e] = ((tid >> e) & 1) ? (u16)0x3F80 : (u16)0;
  }
  __syncthreads();

  unsigned ep = 0;
  for (int t = 0; t < TSTEPS; t++) {
    phase_in<P>(bid, tid, a.data + (size_t)t * BATCH * INDIM, a.w0, a.b0,
                a.mem0, a.pk0, sh);
    if (t > 0 && bid < 16)
      phase_out<P>(bid, tid, a.pk3, a.w4, a.b4, a.mem4,
                   a.out + (size_t)(t - 1) * BATCH * ODIM, sh);
    gridbar(a.cnt, ++ep);
    phase_hid<P>(bid, tid, a.pk0, a.pk1, a.w1, a.b1, a.mem1, sh);
    gridbar(a.cnt, ++ep);
    phase_hid<P>(bid, tid, a.pk1, a.pk2, a.w2, a.b2, a.mem2, sh);
    gridbar(a.cnt, ++ep);
    phase_hid<P>(bid, tid, a.pk2, a.pk3, a.w3, a.b3, a.mem3, sh);
    gridbar(a.cnt, ++ep);
  }
  if (bid < 16)
    phase_out<P>(bid, tid, a.pk3, a.w4, a.b4, a.mem4,
                 a.out + (size_t)(TSTEPS - 1) * BATCH * ODIM, sh);
}

// ------------------------------ host ------------------------------
template<int P>
static void launch_all(const KArgs& ka,
                       const float* W0, const float* W1, const float* W2,
                       const float* W3, const float* W4, hipStream_t s) {
  int n4 = (256 + 4 * BATCH * HID * 4 + BATCH * 32 * 4) / 16;
  k_zero<<<dim3(1024), dim3(256), 0, s>>>((float4*)ka.cnt, n4);

  int nc0 = JT_HID * KS_IN * 64;
  k_split<<<dim3(nc0 / 256), dim3(256), 0, s>>>(W0, (u16*)ka.w0, HID, INDIM, KS_IN, nc0, P, PS_IN);
  int nch = JT_HID * KS_HID * 64;
  k_split<<<dim3(nch / 256), dim3(256), 0, s>>>(W1, (u16*)ka.w1, HID, HID, KS_HID, nch, P, PS_HID);
  k_split<<<dim3(nch / 256), dim3(256), 0, s>>>(W2, (u16*)ka.w2, HID, HID, KS_HID, nch, P, PS_HID);
  k_split<<<dim3(nch / 256), dim3(256), 0, s>>>(W3, (u16*)ka.w3, HID, HID, KS_HID, nch, P, PS_HID);
  int nc4 = 2 * KS_HID * 64;
  k_split<<<dim3(nc4 / 256), dim3(256), 0, s>>>(W4, (u16*)ka.w4, ODIM, HID, KS_HID, nc4, P, PS_OUT);

  KArgs args = ka;
  void* kp[] = { &args };
  hipLaunchCooperativeKernel(reinterpret_cast<const void*>(&k_all<P>),
                             dim3(256), dim3(512), kp, 0, s);
}

extern "C" void kernel_launch(void* const* d_in, const int* in_sizes, int n_in,
                              void* d_out, int out_size, void* d_ws, size_t ws_size,
                              hipStream_t stream) {
  (void)in_sizes; (void)n_in; (void)out_size;
  const float* data = (const float*)d_in[0];
  const float* W0 = (const float*)d_in[1];  const float* b0 = (const float*)d_in[2];
  const float* W1 = (const float*)d_in[3];  const float* b1 = (const float*)d_in[4];
  const float* W2 = (const float*)d_in[5];  const float* b2 = (const float*)d_in[6];
  const float* W3 = (const float*)d_in[7];  const float* b3 = (const float*)d_in[8];
  const float* W4 = (const float*)d_in[9];  const float* b4 = (const float*)d_in[10];

  uint8_t* ws = (uint8_t*)d_ws;
  size_t off = 0;
  auto take = [&](size_t bytes) -> uint8_t* { uint8_t* r = ws + off; off += bytes; return r; };

  KArgs ka;
  ka.data = data;
  ka.b0 = b0; ka.b1 = b1; ka.b2 = b2; ka.b3 = b3; ka.b4 = b4;
  ka.out = (float*)d_out;

  ka.cnt  = (unsigned int*)take(256);                 // zeroed with mems
  ka.mem0 = (float*)take((size_t)BATCH * HID * 4);
  ka.mem1 = (float*)take((size_t)BATCH * HID * 4);
  ka.mem2 = (float*)take((size_t)BATCH * HID * 4);
  ka.mem3 = (float*)take((size_t)BATCH * HID * 4);
  ka.mem4 = (float*)take((size_t)BATCH * 32 * 4);
  ka.pk0  = (u64*)take(128 * 64 * 8);                 // 64 KB each
  ka.pk1  = (u64*)take(128 * 64 * 8);
  ka.pk2  = (u64*)take(128 * 64 * 8);
  ka.pk3  = (u64*)take(128 * 64 * 8);

  size_t fixed = off;
  size_t per_set = 2 * (PS_IN + 3 * PS_HID + PS_OUT);   // bytes per plane-set
  int P = 3;
  if (fixed + 3 * per_set > ws_size) P = 2;
  if (fixed + 2 * per_set > ws_size) P = 1;

  ka.w0 = (u16*)take((size_t)P * PS_IN * 2);
  ka.w1 = (u16*)take((size_t)P * PS_HID * 2);
  ka.w2 = (u16*)take((size_t)P * PS_HID * 2);
  ka.w3 = (u16*)take((size_t)P * PS_HID * 2);
  ka.w4 = (u16*)take((size_t)P * PS_OUT * 2);

  if (P == 3)      launch_all<3>(ka, W0, W1, W2, W3, W4, stream);
  else if (P == 2) launch_all<2>(ka, W0, W1, W2, W3, W4, stream);
  else             launch_all<1>(ka, W0, W1, W2, W3, W4, stream);
}